// Round 12
// baseline (2466.815 us; speedup 1.0000x reference)
//
#include <hip/hip_runtime.h>

#define B 4
#define N 8192
#define F 64
#define S 2048
#define K 16
#define C 128
#define R (B*S*K)   // 131072 rows

typedef float v2f __attribute__((ext_vector_type(2)));

// ---------- exact-arithmetic helpers (match numpy op order, no fma fusion) ----------
__device__ __forceinline__ float norm2f(float x, float y, float z) {
#pragma clang fp contract(off)
  return (x*x + y*y) + z*z;
}

__device__ __forceinline__ float knn_d2(float4 q, float4 p) {
#pragma clang fp contract(off)
  float dot = (q.x*p.x + q.y*p.y) + q.z*p.z;
  return (q.w + p.w) - 2.0f*dot;           // (qn+pn) - 2*dot, reference order
}

// opaque def: forbids rematerialization of the value -> stays in a VGPR
__device__ __forceinline__ void pinf(float& v) { asm volatile("" : "+v"(v)); }

// packed f32 ops via inline asm (compiler never auto-emits VOP3P f32 packed math).
// Element-wise with standard IEEE rounding -> bit-exact vs scalar per-element ops.
__device__ __forceinline__ v2f pk_add(v2f a, v2f b) {
  v2f d; asm("v_pk_add_f32 %0, %1, %2" : "=v"(d) : "v"(a), "v"(b)); return d;
}
__device__ __forceinline__ v2f pk_mul_sq(v2f a) {
  v2f d; asm("v_pk_mul_f32 %0, %1, %1" : "=v"(d) : "v"(a)); return d;
}

// ---------- DPP cross-lane (VALU pipe). bound_ctrl=1 -> invalid lanes read 0:
// identity-safe for u32/u64 max of positive values. HW-verified rounds 2-11.
#define DPP_U(v, ctrl) ((unsigned)__builtin_amdgcn_update_dpp(0, (int)(v), ctrl, 0xf, 0xf, true))
__device__ __forceinline__ unsigned umaxu(unsigned a, unsigned b) { return a > b ? a : b; }

#define WAVE_MAX_U(x) do { \
  x = umaxu(x, DPP_U(x,0x111)); x = umaxu(x, DPP_U(x,0x112)); \
  x = umaxu(x, DPP_U(x,0x114)); x = umaxu(x, DPP_U(x,0x118)); \
  x = umaxu(x, DPP_U(x,0x142)); x = umaxu(x, DPP_U(x,0x143)); } while(0)

// u64 max across the wave: per stage, DPP both halves then 64-bit compare-select.
#define DPP_U64(v, ctrl) ( ((unsigned long long)DPP_U((unsigned)((v)>>32), ctrl) << 32) \
                         | (unsigned long long)DPP_U((unsigned)(v), ctrl) )
#define WAVE_MAX_U64(x) do { \
  unsigned long long o_; \
  o_ = DPP_U64(x,0x111); x = (o_ > x) ? o_ : x; \
  o_ = DPP_U64(x,0x112); x = (o_ > x) ? o_ : x; \
  o_ = DPP_U64(x,0x114); x = (o_ > x) ? o_ : x; \
  o_ = DPP_U64(x,0x118); x = (o_ > x) ? o_ : x; \
  o_ = DPP_U64(x,0x142); x = (o_ > x) ? o_ : x; \
  o_ = DPP_U64(x,0x143); x = (o_ > x) ? o_ : x; } while(0)

// ---------- prep: pad xyz to float4 with |p|^2 in w ----------
__global__ void prep_kernel(const float* __restrict__ xyz, float4* __restrict__ pts4) {
  int i = blockIdx.x*blockDim.x + threadIdx.x;   // B*N
  if (i >= B*N) return;
  float x = xyz[i*3+0], y = xyz[i*3+1], z = xyz[i*3+2];
  pts4[i] = make_float4(x, y, z, norm2f(x, y, z));
}

// ---------- transpose w1 [o][c] -> w1t [c][o] for contiguous scalar weight loads ----------
__global__ void transpose_w1_kernel(const float* __restrict__ w1, float* __restrict__ w1t) {
  int i = blockIdx.x*256 + threadIdx.x;    // C*C = 16384
  int o = i >> 7, c = i & 127;
  w1t[c*C + o] = w1[o*C + c];
}

// ---------- FPS: one block per batch, 256 threads (r11 verified structure).
// Distance update via hand-emitted v_pk_*_f32 (VOP3P packed f32): dx=px+(-wx)
// is IEEE-exact subtraction; ((dx2+dy2)+dz2) association preserved per element.
// Reduction: single u64 lex chain + monotone LDS atomicMax (r11 verified). ----------
__global__ __launch_bounds__(256, 1) void fps_kernel(const float4* __restrict__ pts4,
                                                     float4* __restrict__ q4,
                                                     float* __restrict__ out_xyz) {
  const int b = blockIdx.x;
  const int t = threadIdx.x;
  const float4* pb = pts4 + b*N;

  __shared__ float4 cw[N];                 // 128 KB point cache (winner lookup, b128 read)
  __shared__ float sqx[S], sqy[S], sqz[S]; // 24 KB winner sequence
  __shared__ unsigned long long redloc;    // single monotonic reduction cell

  // thread t owns points i*256+t, i=0..31, paired (2j, 2j+1); pinned in VGPRs
  v2f px[16], py[16], pz[16], md[16];
#pragma unroll
  for (int j = 0; j < 16; ++j) {
    int i0 = (2*j)*256 + t, i1 = (2*j+1)*256 + t;
    float4 v0 = pb[i0];                    // coalesced
    float4 v1 = pb[i1];
    cw[i0] = v0; cw[i1] = v1;
    pinf(v0.x); pinf(v0.y); pinf(v0.z);
    pinf(v1.x); pinf(v1.y); pinf(v1.z);
    px[j] = (v2f){v0.x, v1.x};
    py[j] = (v2f){v0.y, v1.y};
    pz[j] = (v2f){v0.z, v1.z};
    md[j] = (v2f){1e10f, 1e10f};           // BIG
  }
  if (t == 0) redloc = 0ull;
  __syncthreads();                         // redloc init + cw visible before use

  float wx, wy, wz;
  { float4 p0 = pb[0]; wx = p0.x; wy = p0.y; wz = p0.z; }  // reference starts at idx 0

  for (int s = 0; ; ++s) {
    if (t == 0) { sqx[s] = wx; sqy[s] = wy; sqz[s] = wz; }
    if (s == S-1) break;

    // packed distance update (8 pk-inst/pair) + two independent argmax chains.
    float wxn = -wx, wyn = -wy, wzn = -wz;           // exact negation
    v2f wxx = (v2f){wxn, wxn}, wyy = (v2f){wyn, wyn}, wzz = (v2f){wzn, wzn};
    float bvA = -1.0f, bvB = -1.0f; int biA = 0, biB = 0;
#pragma unroll
    for (int j = 0; j < 16; ++j) {
      v2f dx = pk_add(px[j], wxx);         // px - wx, exact
      v2f dy = pk_add(py[j], wyy);
      v2f dz = pk_add(pz[j], wzz);
      v2f sx = pk_mul_sq(dx);              // dx*dx
      v2f sy = pk_mul_sq(dy);
      v2f sz = pk_mul_sq(dz);
      v2f a1 = pk_add(sx, sy);             // (dx2+dy2)
      v2f d  = pk_add(a1, sz);             // ((dx2+dy2)+dz2), per-element rounding
      float m0 = fminf(md[j].x, d.x);
      float m1 = fminf(md[j].y, d.y);
      md[j] = (v2f){m0, m1};
      if (j < 8) {                         // chain A: slots 0..15
        bool g0 = m0 > bvA;  bvA = g0 ? m0 : bvA;  biA = g0 ? (2*j)   : biA;
        bool g1 = m1 > bvA;  bvA = g1 ? m1 : bvA;  biA = g1 ? (2*j+1) : biA;
      } else {                             // chain B: slots 16..31
        bool g0 = m0 > bvB;  bvB = g0 ? m0 : bvB;  biB = g0 ? (2*j)   : biB;
        bool g1 = m1 > bvB;  bvB = g1 ? m1 : bvB;  biB = g1 ? (2*j+1) : biB;
      }
    }
    // merge chains: strict > keeps A (lower slots = lower global idx) on ties
    bool gB = bvB > bvA;
    float bv = gB ? bvB : bvA;             // bv >= 0 always
    int   bi = gB ? biB : biA;

    // pack: (s+1)<<45 | bv_bits<<13 | (8191 - oi); oi = bi*256 + t (13 bits).
    unsigned key = 8191u - (((unsigned)bi << 8) + (unsigned)t);
    unsigned long long pk = ((unsigned long long)(unsigned)(s+1) << 45)
                          | ((unsigned long long)__float_as_uint(bv) << 13)
                          | (unsigned long long)key;
    WAVE_MAX_U64(pk);                      // lane 63 holds wave max
    if ((t & 63) == 63) atomicMax(&redloc, pk);   // ds_max_u64, 4 waves -> 1 cell
    __syncthreads();                       // all atomics visible; single barrier/step

    unsigned long long rw = redloc;        // same-address broadcast read
    int w = 8191 - (int)((unsigned)rw & 0x1FFFu); // winner original index
    float4 pw = cw[w];                     // one same-address ds_read_b128 broadcast
    wx = pw.x; wy = pw.y; wz = pw.z;
  }

  __syncthreads();                         // seq complete
#pragma unroll
  for (int i = t; i < S; i += 256) {
    float x = sqx[i], y = sqy[i], z = sqz[i];
    q4[b*S + i] = make_float4(x, y, z, norm2f(x, y, z));
    out_xyz[(b*S + i)*3 + 0] = x;
    out_xyz[(b*S + i)*3 + 1] = y;
    out_xyz[(b*S + i)*3 + 2] = z;
  }
}

// ---------- KNN: one WAVE per query; per-lane sorted top-16 over 128 points,
// then exact 16-round DPP extraction merge (min d, tie -> min point index) ----------
__global__ __launch_bounds__(256, 4) void knn_kernel(const float4* __restrict__ pts4,
                                                     const float4* __restrict__ q4,
                                                     int* __restrict__ knn) {
  const int gtid = blockIdx.x*256 + threadIdx.x;
  const int wave = gtid >> 6;              // query id, 0..B*S-1
  const int lane = threadIdx.x & 63;
  const int b = wave >> 11;                // S = 2048
  const float4* pb = pts4 + (size_t)b*N;
  float4 q = q4[wave];                     // same addr across wave -> broadcast

  float dv[16]; int di[16];
#pragma unroll
  for (int j = 0; j < 16; ++j) { dv[j] = 3.4e38f; di[j] = 0x7FFFFFFF; }

  // scan: lane owns points n = j*64 + lane (ascending -> within-lane ties keep lower idx)
  for (int j = 0; j < N/64; ++j) {
    int n = j*64 + lane;
    float4 p = pb[n];                      // coalesced global_load_dwordx4
    float d2 = knn_d2(q, p);
#pragma unroll
    for (int k = 15; k >= 1; --k) {
      bool s1 = d2 < dv[k-1];              // strict: incumbent (earlier idx) wins ties
      bool s2 = d2 < dv[k];
      dv[k] = fmaxf(dv[k-1], fminf(d2, dv[k]));   // med3: sorted-insert value update
      di[k] = s1 ? di[k-1] : (s2 ? n : di[k]);
    }
    bool s0 = d2 < dv[0];
    dv[0] = fminf(d2, dv[0]);
    di[0] = s0 ? n : di[0];
  }

  // merge: 16 extraction rounds over the 64 sorted lane-lists
  int myg = 0;
#pragma unroll 1
  for (int r = 0; r < 16; ++r) {
    unsigned bits = __float_as_uint(dv[0]);
    unsigned ord  = bits ^ (0x80000000u | (unsigned)(((int)bits) >> 31));
    unsigned mk   = ~ord;                  // max(mk) == min distance (total order)
    unsigned m = mk;
    WAVE_MAX_U(m);
    unsigned wm = (unsigned)__builtin_amdgcn_readlane((int)m, 63);
    unsigned ci = (mk == wm) ? ~(unsigned)di[0] : 0u;
    unsigned m2 = ci;
    WAVE_MAX_U(m2);
    unsigned wi = (unsigned)__builtin_amdgcn_readlane((int)m2, 63);
    int g = (int)~wi;                      // winning global point index
    if (lane == r) myg = g;
    bool win = (mk == wm) && ((unsigned)di[0] == ~wi);
#pragma unroll
    for (int k = 0; k < 15; ++k) {
      dv[k] = win ? dv[k+1] : dv[k];
      di[k] = win ? di[k+1] : di[k];
    }
    dv[15] = win ? 3.4e38f    : dv[15];
    di[15] = win ? 0x7FFFFFFF : di[15];
  }
  if (lane < 16) knn[wave*16 + lane] = myg;   // coalesced 16-wide store
}

// ---------- GEMM0: gather row (3 xyz-norm + 64 feat) and multiply by w0 [128x67] ----------
__global__ __launch_bounds__(256, 2) void gemm0_kernel(const float4* __restrict__ pts4,
                                                       const float4* __restrict__ q4,
                                                       const float* __restrict__ feat,
                                                       const int* __restrict__ knn,
                                                       const float* __restrict__ w0,
                                                       const float* __restrict__ b0,
                                                       float* __restrict__ Z) {
  int r = blockIdx.x*256 + threadIdx.x;    // 0..R-1
  int bs = r >> 4;                         // b*S + s
  int b  = r >> 15;                        // S*K = 32768 rows per batch
  int p  = knn[r];
  float4 q  = q4[bs];
  float4 pp = pts4[b*N + p];

  float row[67];
  row[0] = pp.x - q.x; row[1] = pp.y - q.y; row[2] = pp.z - q.z;
  const float4* fp = (const float4*)(feat + (size_t)(b*N + p)*F);
#pragma unroll
  for (int i = 0; i < 16; ++i) {
    float4 v = fp[i];
    row[3+4*i] = v.x; row[4+4*i] = v.y; row[5+4*i] = v.z; row[6+4*i] = v.w;
  }

  float* zr = Z + (size_t)r*C;
  for (int og = 0; og < C/4; ++og) {
    float a0 = b0[og*4+0], a1 = b0[og*4+1], a2 = b0[og*4+2], a3 = b0[og*4+3];
    const float* wr = w0 + og*4*67;        // uniform -> scalar loads
#pragma unroll
    for (int c = 0; c < 67; ++c) {
      float x = row[c];
      a0 = fmaf(x, wr[c      ], a0);
      a1 = fmaf(x, wr[67  + c], a1);
      a2 = fmaf(x, wr[134 + c], a2);
      a3 = fmaf(x, wr[201 + c], a3);
    }
    ((float4*)zr)[og] = make_float4(a0, a1, a2, a3);
  }
}

// ---------- per-channel stats partials: sum and sumsq over rows ----------
__global__ void stats_kernel(const float* __restrict__ Z, float* __restrict__ part) {
  int c = threadIdx.x & 127;
  int g = threadIdx.x >> 7;                // 0/1
  int chunk = blockIdx.x*2 + g;            // 0..255
  const int rows = R/256;                  // 512
  const float* zp = Z + (size_t)chunk*rows*C + c;
  float s1 = 0.f, s2 = 0.f;
  for (int j = 0; j < rows; ++j) {
    float v = zp[(size_t)j*C];
    s1 += v;
    s2 = fmaf(v, v, s2);
  }
  __shared__ float sh[2][2][128];
  sh[g][0][c] = s1; sh[g][1][c] = s2;
  __syncthreads();
  if (g == 0) {
    part[(blockIdx.x*128 + c)*2 + 0] = s1 + sh[1][0][c];
    part[(blockIdx.x*128 + c)*2 + 1] = s2 + sh[1][1][c];
  }
}

// ---------- finalize BN: A = gamma*rstd, B = beta - mean*gamma*rstd ----------
__global__ void finalize_kernel(const float* __restrict__ part,
                                const float* __restrict__ gamma,
                                const float* __restrict__ beta,
                                float* __restrict__ AB) {
  int c = threadIdx.x;                     // 128 threads
  float s1 = 0.f, s2 = 0.f;
  for (int i = 0; i < 128; ++i) {
    s1 += part[(i*128 + c)*2 + 0];
    s2 += part[(i*128 + c)*2 + 1];
  }
  const float inv = 1.0f/(float)R;
  float mean = s1*inv;
  float var  = s2*inv - mean*mean;         // biased variance
  float rstd = rsqrtf(var + 1e-5f);
  float a = gamma[c]*rstd;
  AB[c]     = a;
  AB[C + c] = beta[c] - mean*a;
}

// ---------- GEMM1: LDS-tiled (64 rows/block), no register spill, in-place on Z ----------
__global__ __launch_bounds__(256, 4) void gemm1_kernel(float* __restrict__ Z,
                                                       const float* __restrict__ AB0,
                                                       const float* __restrict__ w1t,
                                                       const float* __restrict__ b1) {
  __shared__ float hs[64 * 129];           // stride 129: 2-way bank aliasing = free
  const int tid = threadIdx.x;
  const size_t base = (size_t)blockIdx.x * 64;

  const float4* Z4 = (const float4*)(Z + base * C);
#pragma unroll
  for (int k = 0; k < 8; ++k) {
    int f = tid + k*256;                   // float4 index, 0..2047
    int row = f >> 5, c4 = f & 31;
    float4 v  = Z4[f];
    float4 A  = ((const float4*)AB0)[c4];
    float4 Bb = ((const float4*)AB0)[32 + c4];
    int lb = row*129 + c4*4;
    hs[lb+0] = fmaxf(fmaf(v.x, A.x, Bb.x), 0.f);
    hs[lb+1] = fmaxf(fmaf(v.y, A.y, Bb.y), 0.f);
    hs[lb+2] = fmaxf(fmaf(v.z, A.z, Bb.z), 0.f);
    hs[lb+3] = fmaxf(fmaf(v.w, A.w, Bb.w), 0.f);
  }
  __syncthreads();

  const int row = tid & 63;
  const int qu  = __builtin_amdgcn_readfirstlane(tid >> 6);  // wave-uniform -> s_loads
  const float* wq = w1t + qu*32;           // w1t[c*C + o]
  float acc[32];
#pragma unroll
  for (int o = 0; o < 32; ++o) acc[o] = b1[qu*32 + o];
  const float* hrow = hs + row*129;
  for (int c = 0; c < C; ++c) {
    float x = hrow[c];
    const float* wr = wq + c*C;            // uniform: s_load_dwordx16 x2
#pragma unroll
    for (int o = 0; o < 32; ++o) acc[o] = fmaf(x, wr[o], acc[o]);
  }
  __syncthreads();

#pragma unroll
  for (int o = 0; o < 32; ++o) hs[row*129 + qu*32 + o] = acc[o];
  __syncthreads();
  float4* Zo = (float4*)(Z + base * C);
#pragma unroll
  for (int k = 0; k < 8; ++k) {
    int f = tid + k*256;
    int row2 = f >> 5, c4 = f & 31;
    int lb = row2*129 + c4*4;
    Zo[f] = make_float4(hs[lb+0], hs[lb+1], hs[lb+2], hs[lb+3]);
  }
}

// ---------- maxpool over K with BN1+ReLU fused ----------
__global__ void maxpool_kernel(const float* __restrict__ Z,
                               const float* __restrict__ AB1,
                               float* __restrict__ outF) {
  int t = blockIdx.x*256 + threadIdx.x;    // B*S*32
  int bs = t >> 5, c4 = t & 31;
  const float4* zp = (const float4*)Z + (size_t)bs*K*(C/4) + c4;
  float4 A  = ((const float4*)AB1)[c4];
  float4 Bb = ((const float4*)(AB1 + C))[c4];
  float4 m = make_float4(-3.4e38f, -3.4e38f, -3.4e38f, -3.4e38f);
#pragma unroll
  for (int k = 0; k < K; ++k) {
    float4 z = zp[(size_t)k*(C/4)];
    m.x = fmaxf(m.x, fmaf(z.x, A.x, Bb.x));
    m.y = fmaxf(m.y, fmaf(z.y, A.y, Bb.y));
    m.z = fmaxf(m.z, fmaf(z.z, A.z, Bb.z));
    m.w = fmaxf(m.w, fmaf(z.w, A.w, Bb.w));
  }
  m.x = fmaxf(m.x, 0.f); m.y = fmaxf(m.y, 0.f);
  m.z = fmaxf(m.z, 0.f); m.w = fmaxf(m.w, 0.f);
  ((float4*)outF)[t] = m;                  // max(relu(x)) == relu(max(x))
}

extern "C" void kernel_launch(void* const* d_in, const int* in_sizes, int n_in,
                              void* d_out, int out_size, void* d_ws, size_t ws_size,
                              hipStream_t stream) {
  const float* xyz      = (const float*)d_in[0];
  const float* features = (const float*)d_in[1];
  const float* w0  = (const float*)d_in[2];
  const float* b0  = (const float*)d_in[3];
  const float* g0  = (const float*)d_in[4];
  const float* be0 = (const float*)d_in[5];
  const float* w1  = (const float*)d_in[6];
  const float* b1  = (const float*)d_in[7];
  const float* g1  = (const float*)d_in[8];
  const float* be1 = (const float*)d_in[9];

  char* wp = (char*)d_ws;
  float4* pts4 = (float4*)wp;  wp += (size_t)B*N*sizeof(float4);     // 512 KB
  float4* q4   = (float4*)wp;  wp += (size_t)B*S*sizeof(float4);     // 128 KB
  int*    knn  = (int*)wp;     wp += (size_t)R*sizeof(int);          // 512 KB
  float*  Z    = (float*)wp;   wp += (size_t)R*C*sizeof(float);      // 64 MB
  float*  part = (float*)wp;   wp += (size_t)128*C*2*sizeof(float);  // 128 KB
  float*  AB0  = (float*)wp;   wp += (size_t)2*C*sizeof(float);
  float*  AB1  = (float*)wp;   wp += (size_t)2*C*sizeof(float);
  float*  w1t  = (float*)wp;   wp += (size_t)C*C*sizeof(float);      // 64 KB

  float* out_xyz  = (float*)d_out;            // [B,S,3]
  float* out_feat = (float*)d_out + B*S*3;    // [B,S,C]

  prep_kernel<<<(B*N)/256, 256, 0, stream>>>(xyz, pts4);
  transpose_w1_kernel<<<(C*C)/256, 256, 0, stream>>>(w1, w1t);
  fps_kernel<<<B, 256, 0, stream>>>(pts4, q4, out_xyz);
  knn_kernel<<<(B*S*64)/256, 256, 0, stream>>>(pts4, q4, knn);
  gemm0_kernel<<<R/256, 256, 0, stream>>>(pts4, q4, features, knn, w0, b0, Z);
  stats_kernel<<<128, 256, 0, stream>>>(Z, part);
  finalize_kernel<<<1, 128, 0, stream>>>(part, g0, be0, AB0);
  gemm1_kernel<<<R/64, 256, 0, stream>>>(Z, AB0, w1t, b1);
  stats_kernel<<<128, 256, 0, stream>>>(Z, part);
  finalize_kernel<<<1, 128, 0, stream>>>(part, g1, be1, AB1);
  maxpool_kernel<<<(B*S*32)/256, 256, 0, stream>>>(Z, AB1, out_feat);
}

// Round 13
// 2331.732 us; speedup vs baseline: 1.0579x; 1.0579x over previous
//
#include <hip/hip_runtime.h>

#define B 4
#define N 8192
#define F 64
#define S 2048
#define K 16
#define C 128
#define R (B*S*K)   // 131072 rows

typedef float v2f __attribute__((ext_vector_type(2)));

// ---------- exact-arithmetic helpers (match numpy op order, no fma fusion) ----------
__device__ __forceinline__ float norm2f(float x, float y, float z) {
#pragma clang fp contract(off)
  return (x*x + y*y) + z*z;
}

__device__ __forceinline__ float knn_d2(float4 q, float4 p) {
#pragma clang fp contract(off)
  float dot = (q.x*p.x + q.y*p.y) + q.z*p.z;
  return (q.w + p.w) - 2.0f*dot;           // (qn+pn) - 2*dot, reference order
}

// opaque def: forbids rematerialization of the value -> stays in a VGPR
__device__ __forceinline__ void pinf(float& v) { asm volatile("" : "+v"(v)); }

// ---------- DPP cross-lane (VALU pipe). bound_ctrl=1 -> invalid lanes read 0:
// identity-safe for u32/u64 max of positive values. HW-verified rounds 2-12.
#define DPP_U(v, ctrl) ((unsigned)__builtin_amdgcn_update_dpp(0, (int)(v), ctrl, 0xf, 0xf, true))
__device__ __forceinline__ unsigned umaxu(unsigned a, unsigned b) { return a > b ? a : b; }

#define WAVE_MAX_U(x) do { \
  x = umaxu(x, DPP_U(x,0x111)); x = umaxu(x, DPP_U(x,0x112)); \
  x = umaxu(x, DPP_U(x,0x114)); x = umaxu(x, DPP_U(x,0x118)); \
  x = umaxu(x, DPP_U(x,0x142)); x = umaxu(x, DPP_U(x,0x143)); } while(0)

// u64 max across the wave: per stage, DPP both halves then 64-bit compare-select.
#define DPP_U64(v, ctrl) ( ((unsigned long long)DPP_U((unsigned)((v)>>32), ctrl) << 32) \
                         | (unsigned long long)DPP_U((unsigned)(v), ctrl) )
#define WAVE_MAX_U64(x) do { \
  unsigned long long o_; \
  o_ = DPP_U64(x,0x111); x = (o_ > x) ? o_ : x; \
  o_ = DPP_U64(x,0x112); x = (o_ > x) ? o_ : x; \
  o_ = DPP_U64(x,0x114); x = (o_ > x) ? o_ : x; \
  o_ = DPP_U64(x,0x118); x = (o_ > x) ? o_ : x; \
  o_ = DPP_U64(x,0x142); x = (o_ > x) ? o_ : x; \
  o_ = DPP_U64(x,0x143); x = (o_ > x) ? o_ : x; } while(0)

// ---------- prep: pad xyz to float4 with |p|^2 in w ----------
__global__ void prep_kernel(const float* __restrict__ xyz, float4* __restrict__ pts4) {
  int i = blockIdx.x*blockDim.x + threadIdx.x;   // B*N
  if (i >= B*N) return;
  float x = xyz[i*3+0], y = xyz[i*3+1], z = xyz[i*3+2];
  pts4[i] = make_float4(x, y, z, norm2f(x, y, z));
}

// ---------- transpose w1 [o][c] -> w1t [c][o] for contiguous scalar weight loads ----------
__global__ void transpose_w1_kernel(const float* __restrict__ w1, float* __restrict__ w1t) {
  int i = blockIdx.x*256 + threadIdx.x;    // C*C = 16384
  int o = i >> 7, c = i & 127;
  w1t[c*C + o] = w1[o*C + c];
}

// ---------- FPS: one block per batch, 256 threads (measured-best config).
// Points pinned in VGPRs; single u64 lexicographic DPP chain (md>=0 => float cmp
// == bit cmp); key = (step+1)<<45 | md_bits<<13 | (8191-oi); monotone step field
// => ONE LDS atomicMax cell, no reset, no tail tree, single barrier/step. ----------
__global__ __launch_bounds__(256, 1) void fps_kernel(const float4* __restrict__ pts4,
                                                     float4* __restrict__ q4,
                                                     float* __restrict__ out_xyz) {
  const int b = blockIdx.x;
  const int t = threadIdx.x;
  const float4* pb = pts4 + b*N;

  __shared__ float4 cw[N];                 // 128 KB point cache (winner lookup, b128 read)
  __shared__ float sqx[S], sqy[S], sqz[S]; // 24 KB winner sequence
  __shared__ unsigned long long redloc;    // single monotonic reduction cell

  // thread t owns points i*256+t, i=0..31, paired (2j, 2j+1); pinned in VGPRs
  v2f px[16], py[16], pz[16], md[16];
#pragma unroll
  for (int j = 0; j < 16; ++j) {
    int i0 = (2*j)*256 + t, i1 = (2*j+1)*256 + t;
    float4 v0 = pb[i0];                    // coalesced
    float4 v1 = pb[i1];
    cw[i0] = v0; cw[i1] = v1;
    pinf(v0.x); pinf(v0.y); pinf(v0.z);
    pinf(v1.x); pinf(v1.y); pinf(v1.z);
    px[j] = (v2f){v0.x, v1.x};
    py[j] = (v2f){v0.y, v1.y};
    pz[j] = (v2f){v0.z, v1.z};
    md[j] = (v2f){1e10f, 1e10f};           // BIG
  }
  if (t == 0) redloc = 0ull;
  __syncthreads();                         // redloc init + cw visible before use

  float wx, wy, wz;
  { float4 p0 = pb[0]; wx = p0.x; wy = p0.y; wz = p0.z; }  // reference starts at idx 0

  for (int s = 0; ; ++s) {
    if (t == 0) { sqx[s] = wx; sqy[s] = wy; sqz[s] = wz; }
    if (s == S-1) break;

    // packed min_d update + two independent argmax chains (slots 0..15 / 16..31).
    // per-element IEEE rounding identical to scalar ((dx*dx+dy*dy)+dz*dz).
    v2f wxx = (v2f){wx, wx}, wyy = (v2f){wy, wy}, wzz = (v2f){wz, wz};
    float bvA = -1.0f, bvB = -1.0f; int biA = 0, biB = 0;
#pragma unroll
    for (int j = 0; j < 16; ++j) {
#pragma clang fp contract(off)
      v2f dx = px[j] - wxx;
      v2f dy = py[j] - wyy;
      v2f dz = pz[j] - wzz;
      v2f d  = (dx*dx + dy*dy) + dz*dz;    // sub-mul-add, no fma
      v2f m;
      m.x = fminf(md[j].x, d.x);
      m.y = fminf(md[j].y, d.y);
      md[j] = m;
      if (j < 8) {                         // chain A: slots 0..15
        bool g0 = m.x > bvA;  bvA = g0 ? m.x : bvA;  biA = g0 ? (2*j)   : biA;
        bool g1 = m.y > bvA;  bvA = g1 ? m.y : bvA;  biA = g1 ? (2*j+1) : biA;
      } else {                             // chain B: slots 16..31
        bool g0 = m.x > bvB;  bvB = g0 ? m.x : bvB;  biB = g0 ? (2*j)   : biB;
        bool g1 = m.y > bvB;  bvB = g1 ? m.y : bvB;  biB = g1 ? (2*j+1) : biB;
      }
    }
    // merge chains: strict > keeps A (lower slots = lower global idx) on ties
    bool gB = bvB > bvA;
    float bv = gB ? bvB : bvA;             // bv >= 0 always (set at j=0 / j=8)
    int   bi = gB ? biB : biA;

    // pack: (s+1)<<45 | bv_bits<<13 | (8191 - oi); oi = bi*256 + t (13 bits).
    // max == (max bv, tie -> min original index); step field makes it monotone.
    unsigned key = 8191u - (((unsigned)bi << 8) + (unsigned)t);
    unsigned long long pk = ((unsigned long long)(unsigned)(s+1) << 45)
                          | ((unsigned long long)__float_as_uint(bv) << 13)
                          | (unsigned long long)key;
    WAVE_MAX_U64(pk);                      // lane 63 holds wave max
    if ((t & 63) == 63) atomicMax(&redloc, pk);   // ds_max_u64, 4 waves -> 1 cell
    __syncthreads();                       // all atomics visible; single barrier/step

    unsigned long long rw = redloc;        // same-address broadcast read
    int w = 8191 - (int)((unsigned)rw & 0x1FFFu); // winner original index
    float4 pw = cw[w];                     // one same-address ds_read_b128 broadcast
    wx = pw.x; wy = pw.y; wz = pw.z;
  }

  __syncthreads();                         // seq complete
#pragma unroll
  for (int i = t; i < S; i += 256) {
    float x = sqx[i], y = sqy[i], z = sqz[i];
    q4[b*S + i] = make_float4(x, y, z, norm2f(x, y, z));
    out_xyz[(b*S + i)*3 + 0] = x;
    out_xyz[(b*S + i)*3 + 1] = y;
    out_xyz[(b*S + i)*3 + 2] = z;
  }
}

// ---------- KNN: one WAVE per query; per-lane sorted top-16 over 128 points,
// then exact 16-round DPP extraction merge (min d, tie -> min point index) ----------
__global__ __launch_bounds__(256, 4) void knn_kernel(const float4* __restrict__ pts4,
                                                     const float4* __restrict__ q4,
                                                     int* __restrict__ knn) {
  const int gtid = blockIdx.x*256 + threadIdx.x;
  const int wave = gtid >> 6;              // query id, 0..B*S-1
  const int lane = threadIdx.x & 63;
  const int b = wave >> 11;                // S = 2048
  const float4* pb = pts4 + (size_t)b*N;
  float4 q = q4[wave];                     // same addr across wave -> broadcast

  float dv[16]; int di[16];
#pragma unroll
  for (int j = 0; j < 16; ++j) { dv[j] = 3.4e38f; di[j] = 0x7FFFFFFF; }

  // scan: lane owns points n = j*64 + lane (ascending -> within-lane ties keep lower idx)
  for (int j = 0; j < N/64; ++j) {
    int n = j*64 + lane;
    float4 p = pb[n];                      // coalesced global_load_dwordx4
    float d2 = knn_d2(q, p);
#pragma unroll
    for (int k = 15; k >= 1; --k) {
      bool s1 = d2 < dv[k-1];              // strict: incumbent (earlier idx) wins ties
      bool s2 = d2 < dv[k];
      dv[k] = fmaxf(dv[k-1], fminf(d2, dv[k]));   // med3: sorted-insert value update
      di[k] = s1 ? di[k-1] : (s2 ? n : di[k]);
    }
    bool s0 = d2 < dv[0];
    dv[0] = fminf(d2, dv[0]);
    di[0] = s0 ? n : di[0];
  }

  // merge: 16 extraction rounds over the 64 sorted lane-lists
  int myg = 0;
#pragma unroll 1
  for (int r = 0; r < 16; ++r) {
    unsigned bits = __float_as_uint(dv[0]);
    unsigned ord  = bits ^ (0x80000000u | (unsigned)(((int)bits) >> 31));
    unsigned mk   = ~ord;                  // max(mk) == min distance (total order)
    unsigned m = mk;
    WAVE_MAX_U(m);
    unsigned wm = (unsigned)__builtin_amdgcn_readlane((int)m, 63);
    unsigned ci = (mk == wm) ? ~(unsigned)di[0] : 0u;
    unsigned m2 = ci;
    WAVE_MAX_U(m2);
    unsigned wi = (unsigned)__builtin_amdgcn_readlane((int)m2, 63);
    int g = (int)~wi;                      // winning global point index
    if (lane == r) myg = g;
    bool win = (mk == wm) && ((unsigned)di[0] == ~wi);
#pragma unroll
    for (int k = 0; k < 15; ++k) {
      dv[k] = win ? dv[k+1] : dv[k];
      di[k] = win ? di[k+1] : di[k];
    }
    dv[15] = win ? 3.4e38f    : dv[15];
    di[15] = win ? 0x7FFFFFFF : di[15];
  }
  if (lane < 16) knn[wave*16 + lane] = myg;   // coalesced 16-wide store
}

// ---------- GEMM0: gather row (3 xyz-norm + 64 feat) and multiply by w0 [128x67] ----------
__global__ __launch_bounds__(256, 2) void gemm0_kernel(const float4* __restrict__ pts4,
                                                       const float4* __restrict__ q4,
                                                       const float* __restrict__ feat,
                                                       const int* __restrict__ knn,
                                                       const float* __restrict__ w0,
                                                       const float* __restrict__ b0,
                                                       float* __restrict__ Z) {
  int r = blockIdx.x*256 + threadIdx.x;    // 0..R-1
  int bs = r >> 4;                         // b*S + s
  int b  = r >> 15;                        // S*K = 32768 rows per batch
  int p  = knn[r];
  float4 q  = q4[bs];
  float4 pp = pts4[b*N + p];

  float row[67];
  row[0] = pp.x - q.x; row[1] = pp.y - q.y; row[2] = pp.z - q.z;
  const float4* fp = (const float4*)(feat + (size_t)(b*N + p)*F);
#pragma unroll
  for (int i = 0; i < 16; ++i) {
    float4 v = fp[i];
    row[3+4*i] = v.x; row[4+4*i] = v.y; row[5+4*i] = v.z; row[6+4*i] = v.w;
  }

  float* zr = Z + (size_t)r*C;
  for (int og = 0; og < C/4; ++og) {
    float a0 = b0[og*4+0], a1 = b0[og*4+1], a2 = b0[og*4+2], a3 = b0[og*4+3];
    const float* wr = w0 + og*4*67;        // uniform -> scalar loads
#pragma unroll
    for (int c = 0; c < 67; ++c) {
      float x = row[c];
      a0 = fmaf(x, wr[c      ], a0);
      a1 = fmaf(x, wr[67  + c], a1);
      a2 = fmaf(x, wr[134 + c], a2);
      a3 = fmaf(x, wr[201 + c], a3);
    }
    ((float4*)zr)[og] = make_float4(a0, a1, a2, a3);
  }
}

// ---------- per-channel stats partials: sum and sumsq over rows ----------
__global__ void stats_kernel(const float* __restrict__ Z, float* __restrict__ part) {
  int c = threadIdx.x & 127;
  int g = threadIdx.x >> 7;                // 0/1
  int chunk = blockIdx.x*2 + g;            // 0..255
  const int rows = R/256;                  // 512
  const float* zp = Z + (size_t)chunk*rows*C + c;
  float s1 = 0.f, s2 = 0.f;
  for (int j = 0; j < rows; ++j) {
    float v = zp[(size_t)j*C];
    s1 += v;
    s2 = fmaf(v, v, s2);
  }
  __shared__ float sh[2][2][128];
  sh[g][0][c] = s1; sh[g][1][c] = s2;
  __syncthreads();
  if (g == 0) {
    part[(blockIdx.x*128 + c)*2 + 0] = s1 + sh[1][0][c];
    part[(blockIdx.x*128 + c)*2 + 1] = s2 + sh[1][1][c];
  }
}

// ---------- finalize BN: A = gamma*rstd, B = beta - mean*gamma*rstd ----------
__global__ void finalize_kernel(const float* __restrict__ part,
                                const float* __restrict__ gamma,
                                const float* __restrict__ beta,
                                float* __restrict__ AB) {
  int c = threadIdx.x;                     // 128 threads
  float s1 = 0.f, s2 = 0.f;
  for (int i = 0; i < 128; ++i) {
    s1 += part[(i*128 + c)*2 + 0];
    s2 += part[(i*128 + c)*2 + 1];
  }
  const float inv = 1.0f/(float)R;
  float mean = s1*inv;
  float var  = s2*inv - mean*mean;         // biased variance
  float rstd = rsqrtf(var + 1e-5f);
  float a = gamma[c]*rstd;
  AB[c]     = a;
  AB[C + c] = beta[c] - mean*a;
}

// ---------- GEMM1: LDS-tiled (64 rows/block), no register spill, in-place on Z ----------
__global__ __launch_bounds__(256, 4) void gemm1_kernel(float* __restrict__ Z,
                                                       const float* __restrict__ AB0,
                                                       const float* __restrict__ w1t,
                                                       const float* __restrict__ b1) {
  __shared__ float hs[64 * 129];           // stride 129: 2-way bank aliasing = free
  const int tid = threadIdx.x;
  const size_t base = (size_t)blockIdx.x * 64;

  const float4* Z4 = (const float4*)(Z + base * C);
#pragma unroll
  for (int k = 0; k < 8; ++k) {
    int f = tid + k*256;                   // float4 index, 0..2047
    int row = f >> 5, c4 = f & 31;
    float4 v  = Z4[f];
    float4 A  = ((const float4*)AB0)[c4];
    float4 Bb = ((const float4*)AB0)[32 + c4];
    int lb = row*129 + c4*4;
    hs[lb+0] = fmaxf(fmaf(v.x, A.x, Bb.x), 0.f);
    hs[lb+1] = fmaxf(fmaf(v.y, A.y, Bb.y), 0.f);
    hs[lb+2] = fmaxf(fmaf(v.z, A.z, Bb.z), 0.f);
    hs[lb+3] = fmaxf(fmaf(v.w, A.w, Bb.w), 0.f);
  }
  __syncthreads();

  const int row = tid & 63;
  const int qu  = __builtin_amdgcn_readfirstlane(tid >> 6);  // wave-uniform -> s_loads
  const float* wq = w1t + qu*32;           // w1t[c*C + o]
  float acc[32];
#pragma unroll
  for (int o = 0; o < 32; ++o) acc[o] = b1[qu*32 + o];
  const float* hrow = hs + row*129;
  for (int c = 0; c < C; ++c) {
    float x = hrow[c];
    const float* wr = wq + c*C;            // uniform: s_load_dwordx16 x2
#pragma unroll
    for (int o = 0; o < 32; ++o) acc[o] = fmaf(x, wr[o], acc[o]);
  }
  __syncthreads();

#pragma unroll
  for (int o = 0; o < 32; ++o) hs[row*129 + qu*32 + o] = acc[o];
  __syncthreads();
  float4* Zo = (float4*)(Z + base * C);
#pragma unroll
  for (int k = 0; k < 8; ++k) {
    int f = tid + k*256;
    int row2 = f >> 5, c4 = f & 31;
    int lb = row2*129 + c4*4;
    Zo[f] = make_float4(hs[lb+0], hs[lb+1], hs[lb+2], hs[lb+3]);
  }
}

// ---------- maxpool over K with BN1+ReLU fused ----------
__global__ void maxpool_kernel(const float* __restrict__ Z,
                               const float* __restrict__ AB1,
                               float* __restrict__ outF) {
  int t = blockIdx.x*256 + threadIdx.x;    // B*S*32
  int bs = t >> 5, c4 = t & 31;
  const float4* zp = (const float4*)Z + (size_t)bs*K*(C/4) + c4;
  float4 A  = ((const float4*)AB1)[c4];
  float4 Bb = ((const float4*)(AB1 + C))[c4];
  float4 m = make_float4(-3.4e38f, -3.4e38f, -3.4e38f, -3.4e38f);
#pragma unroll
  for (int k = 0; k < K; ++k) {
    float4 z = zp[(size_t)k*(C/4)];
    m.x = fmaxf(m.x, fmaf(z.x, A.x, Bb.x));
    m.y = fmaxf(m.y, fmaf(z.y, A.y, Bb.y));
    m.z = fmaxf(m.z, fmaf(z.z, A.z, Bb.z));
    m.w = fmaxf(m.w, fmaf(z.w, A.w, Bb.w));
  }
  m.x = fmaxf(m.x, 0.f); m.y = fmaxf(m.y, 0.f);
  m.z = fmaxf(m.z, 0.f); m.w = fmaxf(m.w, 0.f);
  ((float4*)outF)[t] = m;                  // max(relu(x)) == relu(max(x))
}

extern "C" void kernel_launch(void* const* d_in, const int* in_sizes, int n_in,
                              void* d_out, int out_size, void* d_ws, size_t ws_size,
                              hipStream_t stream) {
  const float* xyz      = (const float*)d_in[0];
  const float* features = (const float*)d_in[1];
  const float* w0  = (const float*)d_in[2];
  const float* b0  = (const float*)d_in[3];
  const float* g0  = (const float*)d_in[4];
  const float* be0 = (const float*)d_in[5];
  const float* w1  = (const float*)d_in[6];
  const float* b1  = (const float*)d_in[7];
  const float* g1  = (const float*)d_in[8];
  const float* be1 = (const float*)d_in[9];

  char* wp = (char*)d_ws;
  float4* pts4 = (float4*)wp;  wp += (size_t)B*N*sizeof(float4);     // 512 KB
  float4* q4   = (float4*)wp;  wp += (size_t)B*S*sizeof(float4);     // 128 KB
  int*    knn  = (int*)wp;     wp += (size_t)R*sizeof(int);          // 512 KB
  float*  Z    = (float*)wp;   wp += (size_t)R*C*sizeof(float);      // 64 MB
  float*  part = (float*)wp;   wp += (size_t)128*C*2*sizeof(float);  // 128 KB
  float*  AB0  = (float*)wp;   wp += (size_t)2*C*sizeof(float);
  float*  AB1  = (float*)wp;   wp += (size_t)2*C*sizeof(float);
  float*  w1t  = (float*)wp;   wp += (size_t)C*C*sizeof(float);      // 64 KB

  float* out_xyz  = (float*)d_out;            // [B,S,3]
  float* out_feat = (float*)d_out + B*S*3;    // [B,S,C]

  prep_kernel<<<(B*N)/256, 256, 0, stream>>>(xyz, pts4);
  transpose_w1_kernel<<<(C*C)/256, 256, 0, stream>>>(w1, w1t);
  fps_kernel<<<B, 256, 0, stream>>>(pts4, q4, out_xyz);
  knn_kernel<<<(B*S*64)/256, 256, 0, stream>>>(pts4, q4, knn);
  gemm0_kernel<<<R/256, 256, 0, stream>>>(pts4, q4, features, knn, w0, b0, Z);
  stats_kernel<<<128, 256, 0, stream>>>(Z, part);
  finalize_kernel<<<1, 128, 0, stream>>>(part, g0, be0, AB0);
  gemm1_kernel<<<R/64, 256, 0, stream>>>(Z, AB0, w1t, b1);
  stats_kernel<<<128, 256, 0, stream>>>(Z, part);
  finalize_kernel<<<1, 128, 0, stream>>>(part, g1, be1, AB1);
  maxpool_kernel<<<(B*S*32)/256, 256, 0, stream>>>(Z, AB1, out_feat);
}